// Round 3
// 72.192 us; speedup vs baseline: 1.0073x; 1.0073x over previous
//
#include <hip/hip_runtime.h>
#include <math.h>

#define Bb   2
#define Vv   20000
#define Cc   9
#define KS   9
#define OUTn 16
#define NB   16
#define LPV  4            // lanes per vertex, 4 neighbors per lane

static_assert(NB % LPV == 0, "neighbors must split evenly across lanes");
static_assert(OUTn % LPV == 0, "outputs must split evenly across lanes");
static_assert((Bb * Vv * LPV) % 256 == 0, "grid must exactly cover work");

// quad all-reduce across lanes {4q, 4q+1, 4q+2, 4q+3} via standard shfl_xor
__device__ __forceinline__ float quad_sum(float x) {
    x += __shfl_xor(x, 1, 64);
    x += __shfl_xor(x, 2, 64);
    return x;
}

__device__ __forceinline__ void loadrow(float (&dst)[Cc],
                                        const float* __restrict__ xb, int j) {
    // j==0 (masked) clamps to row 0; contribution is zeroed via the mask.
    const float* p = xb + (j > 0 ? j - 1 : 0) * Cc;
    #pragma unroll
    for (int c = 0; c < Cc; ++c) dst[c] = p[c];
}

__device__ __forceinline__ void accum(const float (&xv)[Cc],
                                      const float (&xn)[Cc],
                                      float mskf,
                                      float (&s)[KS][Cc]) {
    float d[Cc];
    float m = -INFINITY;
    #pragma unroll
    for (int c = 0; c < Cc; ++c) { d[c] = xv[c] - xn[c]; m = fmaxf(m, d[c]); }
    float sum = 0.0f;
    #pragma unroll
    for (int c = 0; c < Cc; ++c) { d[c] = __expf(d[c] - m); sum += d[c]; }
    // fold neighbor mask into the softmax normalizer: masked -> q == 0
    float invs = mskf / sum;
    #pragma unroll
    for (int k = 0; k < KS; ++k) {
        float qk = d[k] * invs;
        #pragma unroll
        for (int c = 0; c < Cc; ++c) s[k][c] = fmaf(qk, xn[c], s[k][c]);
    }
}

__global__ __launch_bounds__(256) void nlayer_kernel(
    const float* __restrict__ x,   // (B,V,C)
    const float* __restrict__ W,   // (C,KS,OUT)
    const int*   __restrict__ adj, // (V,NB)
    float* __restrict__ out)       // (B,V,OUT)
{
    __shared__ float4 sW[(Cc * KS * OUTn) / 4];   // 324 float4 = 5184 B
    {
        const float4* Wv = (const float4*)W;
        int t = threadIdx.x;
        if (t < (Cc * KS * OUTn) / 4) sW[t] = Wv[t];
        t += 256;
        if (t < (Cc * KS * OUTn) / 4) sW[t] = Wv[t];
    }
    __syncthreads();

    const int tid  = blockIdx.x * 256 + threadIdx.x;
    const int vert = tid >> 2;                        // 0 .. B*V-1
    if (vert >= Bb * Vv) return;                      // defensive (grid exact)
    const int sl   = tid & 3;                         // sub-lane within vertex
    const int b    = vert / Vv;
    const int v    = vert - b * Vv;

    // coalesced adj read: each lane grabs its 4 neighbor ids as one int4
    const int4 aj = ((const int4*)adj)[v * (NB / 4) + sl];

    const float* xb = x + b * (Vv * Cc);

    float xv[Cc];
    #pragma unroll
    for (int c = 0; c < Cc; ++c) xv[c] = xb[v * Cc + c];

    float s[KS][Cc];
    #pragma unroll
    for (int k = 0; k < KS; ++k)
        #pragma unroll
        for (int c = 0; c < Cc; ++c) s[k][c] = 0.0f;

    const float m0 = (aj.x != 0) ? 1.0f : 0.0f;
    const float m1 = (aj.y != 0) ? 1.0f : 0.0f;
    const float m2 = (aj.z != 0) ? 1.0f : 0.0f;
    const float m3 = (aj.w != 0) ? 1.0f : 0.0f;

    // 2-deep software pipeline: 2 gathered rows in flight, branchless
    float xnA[Cc], xnB[Cc];
    loadrow(xnA, xb, aj.x);
    loadrow(xnB, xb, aj.y);
    accum(xv, xnA, m0, s);
    loadrow(xnA, xb, aj.z);
    accum(xv, xnB, m1, s);
    loadrow(xnB, xb, aj.w);
    accum(xv, xnA, m2, s);
    accum(xv, xnB, m3, s);

    // reduce deg and s across the 4 lanes of this vertex
    float degf = quad_sum(m0 + m1 + m2 + m3);
    #pragma unroll
    for (int k = 0; k < KS; ++k)
        #pragma unroll
        for (int c = 0; c < Cc; ++c) s[k][c] = quad_sum(s[k][c]);

    const float invdeg = (degf > 0.0f) ? (1.0f / degf) : 0.0f;

    // final contraction: lane sl produces outputs 4*sl .. 4*sl+3
    float4 acc = make_float4(0.f, 0.f, 0.f, 0.f);
    #pragma unroll
    for (int c = 0; c < Cc; ++c) {
        #pragma unroll
        for (int k = 0; k < KS; ++k) {
            const float  sv = s[k][c];
            const float4 w4 = sW[(c * KS + k) * (OUTn / 4) + sl];
            acc.x = fmaf(sv, w4.x, acc.x);
            acc.y = fmaf(sv, w4.y, acc.y);
            acc.z = fmaf(sv, w4.z, acc.z);
            acc.w = fmaf(sv, w4.w, acc.w);
        }
    }

    float4 r;
    r.x = fmaxf(acc.x * invdeg, 0.0f);
    r.y = fmaxf(acc.y * invdeg, 0.0f);
    r.z = fmaxf(acc.z * invdeg, 0.0f);
    r.w = fmaxf(acc.w * invdeg, 0.0f);
    ((float4*)out)[vert * (OUTn / 4) + sl] = r;
}

extern "C" void kernel_launch(void* const* d_in, const int* in_sizes, int n_in,
                              void* d_out, int out_size, void* d_ws, size_t ws_size,
                              hipStream_t stream) {
    const float* x   = (const float*)d_in[0];
    const float* W   = (const float*)d_in[1];
    const int*   adj = (const int*)d_in[2];
    float*       out = (float*)d_out;

    const int total = Bb * Vv * LPV;         // 160000 threads, 4 per (b,v)
    const int block = 256;
    const int grid  = total / block;         // 625 blocks == exact cover
    nlayer_kernel<<<grid, block, 0, stream>>>(x, W, adj, out);
}